// Round 1
// baseline (612.233 us; speedup 1.0000x reference)
//
#include <hip/hip_runtime.h>
#include <cstdint>
#include <cstddef>

// Multi-resolution hash encoding (Instant-NGP style), MI355X.
//
// Mapping: one thread per (point, level) pair, tid = n*16 + l.
//  - lanes with consecutive tid write consecutive float2 -> fully coalesced
//    8B/lane output stores (nontemporal, to keep hash table resident in L2).
//  - 4 points per wave64; x[n] loads broadcast from L1.
// Inputs (setup_inputs order):
//   d_in[0] = x           [N,3]  f32
//   d_in[1] = hash_table  [TABLE_SIZE*L, 2] f32
//   d_in[2] = scalings    [L]    f32
//   d_in[3] = hash_offset [L]    i32
//   d_in[4] = table_size  scalar i32
// Output: [N, L*2] f32.

typedef float f32x2 __attribute__((ext_vector_type(2)));

#define NUM_LEVELS 16

__global__ __launch_bounds__(256) void hashenc_kernel(
    const float* __restrict__ x,
    const float* __restrict__ table,
    const float* __restrict__ scalings,
    const int* __restrict__ hash_offset,
    const int* __restrict__ tsp,
    float* __restrict__ out,
    int n_points)
{
    const int tid = blockIdx.x * blockDim.x + threadIdx.x;
    const int total = n_points * NUM_LEVELS;
    if (tid >= total) return;

    const int n = tid >> 4;       // point index
    const int l = tid & 15;       // level index

    const float px = x[n * 3 + 0];
    const float py = x[n * 3 + 1];
    const float pz = x[n * 3 + 2];

    const float s  = scalings[l];
    const float sx = px * s;
    const float sy = py * s;
    const float sz = pz * s;

    const float fxf = floorf(sx), fyf = floorf(sy), fzf = floorf(sz);
    const float cxf = ceilf(sx),  cyf = ceilf(sy),  czf = ceilf(sz);
    const float tx = sx - fxf, ty = sy - fyf, tz = sz - fzf;

    // Corner coords are non-negative integral floats; cast exact.
    const uint32_t fxi = (uint32_t)(int)fxf, fyi = (uint32_t)(int)fyf, fzi = (uint32_t)(int)fzf;
    const uint32_t cxi = (uint32_t)(int)cxf, cyi = (uint32_t)(int)cyf, czi = (uint32_t)(int)czf;

    // NGP hash: (ix*1) ^ (iy*P1) ^ (iz*P2), uint32 wraparound.
    const uint32_t P1 = 2654435761u, P2 = 805459861u;
    const uint32_t hyf = fyi * P1, hyc = cyi * P1;
    const uint32_t hzf = fzi * P2, hzc = czi * P2;

    uint32_t h[8];
    h[0] = cxi ^ hyc ^ hzc;   // v0 (c,c,c)
    h[1] = cxi ^ hyc ^ hzf;   // v1 (c,c,f)
    h[2] = cxi ^ hyf ^ hzc;   // v2 (c,f,c)
    h[3] = fxi ^ hyc ^ hzc;   // v3 (f,c,c)
    h[4] = cxi ^ hyf ^ hzf;   // v4 (c,f,f)
    h[5] = fxi ^ hyc ^ hzf;   // v5 (f,c,f)
    h[6] = fxi ^ hyf ^ hzc;   // v6 (f,f,c)
    h[7] = fxi ^ hyf ^ hzf;   // v7 (f,f,f)

    const uint32_t ts  = (uint32_t)tsp[0];
    const int      off = hash_offset[l];
    const bool pow2 = (ts & (ts - 1u)) == 0u;   // wave-uniform branch
    const uint32_t mask = ts - 1u;

    f32x2 f[8];
#pragma unroll
    for (int c = 0; c < 8; ++c) {
        const uint32_t hm = pow2 ? (h[c] & mask) : (h[c] % ts);
        const size_t idx = (size_t)((int)hm + off);
        f[c] = *reinterpret_cast<const f32x2*>(table + idx * 2);
    }

    const float ux = 1.f - tx, uy = 1.f - ty, uz = 1.f - tz;
    float w[8];
    w[0] = tx * ty * tz;
    w[1] = tx * uy * tz;
    w[2] = ux * uy * tz;
    w[3] = ux * ty * tz;
    w[4] = tx * ty * uz;
    w[5] = tx * uy * uz;
    w[6] = ux * uy * uz;
    w[7] = ux * ty * uz;

    f32x2 acc = {0.f, 0.f};
#pragma unroll
    for (int c = 0; c < 8; ++c) {
        acc.x = fmaf(w[c], f[c].x, acc.x);
        acc.y = fmaf(w[c], f[c].y, acc.y);
    }

    // Nontemporal: 67MB output stream must not evict the L2-resident tables.
    __builtin_nontemporal_store(acc, reinterpret_cast<f32x2*>(out) + tid);
}

extern "C" void kernel_launch(void* const* d_in, const int* in_sizes, int n_in,
                              void* d_out, int out_size, void* d_ws, size_t ws_size,
                              hipStream_t stream) {
    const float* x           = (const float*)d_in[0];
    const float* hash_table  = (const float*)d_in[1];
    const float* scalings    = (const float*)d_in[2];
    const int*   hash_offset = (const int*)d_in[3];
    const int*   table_size  = (const int*)d_in[4];
    float*       out         = (float*)d_out;

    const int n_points = in_sizes[0] / 3;
    const int total    = n_points * NUM_LEVELS;
    const int block    = 256;
    const int grid     = (total + block - 1) / block;

    hashenc_kernel<<<grid, block, 0, stream>>>(
        x, hash_table, scalings, hash_offset, table_size, out, n_points);
}

// Round 2
// 554.024 us; speedup vs baseline: 1.1051x; 1.1051x over previous
//
#include <hip/hip_runtime.h>
#include <cstdint>
#include <cstddef>

// Instant-NGP multires hash encoding, MI355X.
//
// Round-2 structure: LEVEL-PARTITIONED gather for L2 locality.
//  - Each level's table slab is <= 4 MB == one XCD's L2. One block = one
//    level x 512 points. XCD-aware mapping (xcd = bid & 7): XCD x processes
//    all of level x, then level x+8, so its L2 holds exactly one slab at a
//    time -> gathers become L2 hits (round 1: 1.82 GB HBM fetch from L2
//    thrash across all 16 slabs).
//  - Gather results staged level-major in d_ws (coalesced f32x2 nontemporal
//    stores), then a streaming transpose writes the [N, 32] output.
//  - Fallback if ws too small: direct strided store to out.

typedef float f32x2 __attribute__((ext_vector_type(2)));
typedef float f32x4 __attribute__((ext_vector_type(4)));

#define NUM_LEVELS 16
#define BLOCK 256
#define PPT 2                    // points per thread (16 gathers in flight)
#define CHUNK (BLOCK * PPT)

__device__ __forceinline__ void hash_point(
    float px, float py, float pz, float s,
    uint32_t ts, uint32_t mask, bool pow2,
    uint32_t h[8], float w[8])
{
    const float sx = px * s, sy = py * s, sz = pz * s;
    const float fxf = floorf(sx), fyf = floorf(sy), fzf = floorf(sz);
    const float cxf = ceilf(sx),  cyf = ceilf(sy),  czf = ceilf(sz);
    const float tx = sx - fxf, ty = sy - fyf, tz = sz - fzf;

    const uint32_t fxi = (uint32_t)(int)fxf, fyi = (uint32_t)(int)fyf, fzi = (uint32_t)(int)fzf;
    const uint32_t cxi = (uint32_t)(int)cxf, cyi = (uint32_t)(int)cyf, czi = (uint32_t)(int)czf;

    const uint32_t P1 = 2654435761u, P2 = 805459861u;
    const uint32_t hyf = fyi * P1, hyc = cyi * P1;
    const uint32_t hzf = fzi * P2, hzc = czi * P2;

    uint32_t r[8];
    r[0] = cxi ^ hyc ^ hzc;   // v0 (c,c,c)
    r[1] = cxi ^ hyc ^ hzf;   // v1 (c,c,f)
    r[2] = cxi ^ hyf ^ hzc;   // v2 (c,f,c)
    r[3] = fxi ^ hyc ^ hzc;   // v3 (f,c,c)
    r[4] = cxi ^ hyf ^ hzf;   // v4 (c,f,f)
    r[5] = fxi ^ hyc ^ hzf;   // v5 (f,c,f)
    r[6] = fxi ^ hyf ^ hzc;   // v6 (f,f,c)
    r[7] = fxi ^ hyf ^ hzf;   // v7 (f,f,f)
#pragma unroll
    for (int c = 0; c < 8; ++c)
        h[c] = pow2 ? (r[c] & mask) : (r[c] % ts);

    const float ux = 1.f - tx, uy = 1.f - ty, uz = 1.f - tz;
    w[0] = tx * ty * tz;
    w[1] = tx * uy * tz;
    w[2] = ux * uy * tz;
    w[3] = ux * ty * tz;
    w[4] = tx * ty * uz;
    w[5] = tx * uy * uz;
    w[6] = ux * uy * uz;
    w[7] = ux * ty * uz;
}

template<bool TO_WS>
__global__ __launch_bounds__(BLOCK) void hashenc_gather(
    const float* __restrict__ x,
    const float* __restrict__ table,
    const float* __restrict__ scalings,
    const int* __restrict__ hash_offset,
    const int* __restrict__ tsp,
    float* __restrict__ dst,          // TO_WS: ws level-major [L][N] f32x2; else out [N][L] f32x2
    int n_points, int bpl)            // bpl = blocks per level
{
    // xcd = bid & 7 (round-robin block->XCD heuristic). XCD x runs level x
    // for bpl blocks, then level x+8. L2 working set = one 4MB slab.
    const int bid   = blockIdx.x;
    const int xcd   = bid & 7;
    const int seq   = bid >> 3;
    const int phase = (seq >= bpl) ? 1 : 0;
    const int chunk = seq - phase * bpl;
    const int level = xcd + (phase << 3);

    const float    s    = scalings[level];
    const int      off  = hash_offset[level];
    const uint32_t ts   = (uint32_t)tsp[0];
    const bool     pow2 = (ts & (ts - 1u)) == 0u;   // uniform branch
    const uint32_t mask = ts - 1u;

    const int n0 = chunk * CHUNK + (int)threadIdx.x;
    const int n1 = n0 + BLOCK;
    const bool v0 = n0 < n_points;
    const bool v1 = n1 < n_points;

    uint32_t h0[8], h1[8];
    float    w0[8], w1[8];
    if (v0) hash_point(x[n0*3], x[n0*3+1], x[n0*3+2], s, ts, mask, pow2, h0, w0);
    if (v1) hash_point(x[n1*3], x[n1*3+1], x[n1*3+2], s, ts, mask, pow2, h1, w1);

    const f32x2* tb = reinterpret_cast<const f32x2*>(table) + off;

    f32x2 f0[8], f1[8];
#pragma unroll
    for (int c = 0; c < 8; ++c) if (v0) f0[c] = tb[h0[c]];
#pragma unroll
    for (int c = 0; c < 8; ++c) if (v1) f1[c] = tb[h1[c]];

    f32x2 a0 = {0.f, 0.f}, a1 = {0.f, 0.f};
#pragma unroll
    for (int c = 0; c < 8; ++c) {
        a0.x = fmaf(w0[c], f0[c].x, a0.x);
        a0.y = fmaf(w0[c], f0[c].y, a0.y);
    }
#pragma unroll
    for (int c = 0; c < 8; ++c) {
        a1.x = fmaf(w1[c], f1[c].x, a1.x);
        a1.y = fmaf(w1[c], f1[c].y, a1.y);
    }

    if (TO_WS) {
        f32x2* wsl = reinterpret_cast<f32x2*>(dst) + (size_t)level * n_points;
        if (v0) __builtin_nontemporal_store(a0, wsl + n0);
        if (v1) __builtin_nontemporal_store(a1, wsl + n1);
    } else {
        f32x2* o = reinterpret_cast<f32x2*>(dst);
        if (v0) __builtin_nontemporal_store(a0, o + (size_t)n0 * NUM_LEVELS + level);
        if (v1) __builtin_nontemporal_store(a1, o + (size_t)n1 * NUM_LEVELS + level);
    }
}

// ws [L][N] f32x2 -> out [N][L] f32x2. Per-lane 128B contiguous writes.
__global__ __launch_bounds__(BLOCK) void hashenc_transpose(
    const float* __restrict__ ws, float* __restrict__ out, int n_points)
{
    const int n = blockIdx.x * BLOCK + (int)threadIdx.x;
    if (n >= n_points) return;

    f32x2 v[NUM_LEVELS];
#pragma unroll
    for (int l = 0; l < NUM_LEVELS; ++l)
        v[l] = __builtin_nontemporal_load(
            reinterpret_cast<const f32x2*>(ws) + (size_t)l * n_points + n);

    f32x4* o = reinterpret_cast<f32x4*>(out + (size_t)n * (NUM_LEVELS * 2));
#pragma unroll
    for (int i = 0; i < 8; ++i) {
        f32x4 t;
        t.x = v[2*i].x;   t.y = v[2*i].y;
        t.z = v[2*i+1].x; t.w = v[2*i+1].y;
        __builtin_nontemporal_store(t, o + i);
    }
}

extern "C" void kernel_launch(void* const* d_in, const int* in_sizes, int n_in,
                              void* d_out, int out_size, void* d_ws, size_t ws_size,
                              hipStream_t stream) {
    const float* x           = (const float*)d_in[0];
    const float* hash_table  = (const float*)d_in[1];
    const float* scalings    = (const float*)d_in[2];
    const int*   hash_offset = (const int*)d_in[3];
    const int*   table_size  = (const int*)d_in[4];
    float*       out         = (float*)d_out;

    const int n_points = in_sizes[0] / 3;
    const int bpl      = (n_points + CHUNK - 1) / CHUNK;   // blocks per level
    const int grid1    = 16 * bpl;                          // 8 xcd-slots x 2 phases

    const size_t ws_needed = (size_t)n_points * NUM_LEVELS * 2 * sizeof(float);

    if (ws_size >= ws_needed) {
        hashenc_gather<true><<<grid1, BLOCK, 0, stream>>>(
            x, hash_table, scalings, hash_offset, table_size,
            (float*)d_ws, n_points, bpl);
        const int grid2 = (n_points + BLOCK - 1) / BLOCK;
        hashenc_transpose<<<grid2, BLOCK, 0, stream>>>(
            (const float*)d_ws, out, n_points);
    } else {
        hashenc_gather<false><<<grid1, BLOCK, 0, stream>>>(
            x, hash_table, scalings, hash_offset, table_size,
            out, n_points, bpl);
    }
}

// Round 3
// 543.956 us; speedup vs baseline: 1.1255x; 1.0185x over previous
//
#include <hip/hip_runtime.h>
#include <cstdint>
#include <cstddef>

// Instant-NGP multires hash encoding, MI355X.
//
// Round-3 structure: TIME-PHASED levels.
//  - Grid is level-major: blocks [slot*bpl, (slot+1)*bpl) process level
//    perm[slot]. Blocks dispatch roughly in bid order, so at any moment the
//    whole chip works on ~1-2 adjacent slots; every XCD's L2 caches the
//    current level's 4MB slab (replicated per-XCD, L3 absorbs refetch).
//    Fixes round-2's static-partition imbalance (occupancy 31% -> tail XCDs
//    owned two expensive levels).
//  - perm alternates big/small levels so slot-boundary straddles co-residence
//    a 4MB slab with a small one.
//  - PPT=1 keeps VGPR low (max waves) and the resident block window ~1 slot.
//  - Gather writes ws level-major (coalesced nt stores), transpose kernel
//    produces [N, 32] with 16B stores.

typedef float f32x2 __attribute__((ext_vector_type(2)));
typedef float f32x4 __attribute__((ext_vector_type(4)));

#define NUM_LEVELS 16
#define BLOCK 256

__global__ __launch_bounds__(BLOCK) void hashenc_gather(
    const float* __restrict__ x,
    const float* __restrict__ table,
    const float* __restrict__ scalings,
    const int* __restrict__ hash_offset,
    const int* __restrict__ tsp,
    float* __restrict__ ws,           // [L][N] f32x2, level-major
    int n_points, int bpl)            // bpl = blocks per level
{
    // Big/small alternation: 15,0,14,1,... then remaining big levels.
    static const int perm_arr[NUM_LEVELS] =
        {15, 0, 14, 1, 13, 2, 12, 3, 11, 4, 10, 9, 8, 7, 6, 5};

    const int bid   = (int)blockIdx.x;
    const int slot  = bid / bpl;                    // wave-uniform
    const int level = perm_arr[slot];
    const int n     = (bid - slot * bpl) * BLOCK + (int)threadIdx.x;
    if (n >= n_points) return;

    const float    s    = scalings[level];
    const int      off  = hash_offset[level];
    const uint32_t ts   = (uint32_t)tsp[0];
    const bool     pow2 = (ts & (ts - 1u)) == 0u;   // uniform branch
    const uint32_t mask = ts - 1u;

    const float px = x[n * 3 + 0];
    const float py = x[n * 3 + 1];
    const float pz = x[n * 3 + 2];

    const float sx = px * s, sy = py * s, sz = pz * s;
    const float fxf = floorf(sx), fyf = floorf(sy), fzf = floorf(sz);
    const float cxf = ceilf(sx),  cyf = ceilf(sy),  czf = ceilf(sz);
    const float tx = sx - fxf, ty = sy - fyf, tz = sz - fzf;

    const uint32_t fxi = (uint32_t)(int)fxf, fyi = (uint32_t)(int)fyf, fzi = (uint32_t)(int)fzf;
    const uint32_t cxi = (uint32_t)(int)cxf, cyi = (uint32_t)(int)cyf, czi = (uint32_t)(int)czf;

    const uint32_t P1 = 2654435761u, P2 = 805459861u;
    const uint32_t hyf = fyi * P1, hyc = cyi * P1;
    const uint32_t hzf = fzi * P2, hzc = czi * P2;

    uint32_t h[8];
    h[0] = cxi ^ hyc ^ hzc;   // v0 (c,c,c)
    h[1] = cxi ^ hyc ^ hzf;   // v1 (c,c,f)
    h[2] = cxi ^ hyf ^ hzc;   // v2 (c,f,c)
    h[3] = fxi ^ hyc ^ hzc;   // v3 (f,c,c)
    h[4] = cxi ^ hyf ^ hzf;   // v4 (c,f,f)
    h[5] = fxi ^ hyc ^ hzf;   // v5 (f,c,f)
    h[6] = fxi ^ hyf ^ hzc;   // v6 (f,f,c)
    h[7] = fxi ^ hyf ^ hzf;   // v7 (f,f,f)

    const f32x2* tb = reinterpret_cast<const f32x2*>(table) + off;

    f32x2 f[8];
#pragma unroll
    for (int c = 0; c < 8; ++c) {
        const uint32_t hm = pow2 ? (h[c] & mask) : (h[c] % ts);
        f[c] = tb[hm];
    }

    const float ux = 1.f - tx, uy = 1.f - ty, uz = 1.f - tz;
    float w[8];
    w[0] = tx * ty * tz;
    w[1] = tx * uy * tz;
    w[2] = ux * uy * tz;
    w[3] = ux * ty * tz;
    w[4] = tx * ty * uz;
    w[5] = tx * uy * uz;
    w[6] = ux * uy * uz;
    w[7] = ux * ty * uz;

    f32x2 acc = {0.f, 0.f};
#pragma unroll
    for (int c = 0; c < 8; ++c) {
        acc.x = fmaf(w[c], f[c].x, acc.x);
        acc.y = fmaf(w[c], f[c].y, acc.y);
    }

    // nt store: don't let the 67MB ws stream evict the L2-resident slab.
    f32x2* wsl = reinterpret_cast<f32x2*>(ws) + (size_t)level * n_points;
    __builtin_nontemporal_store(acc, wsl + n);
}

// ws [L][N] f32x2 -> out [N][L] f32x2. Loads coalesced per level (wave reads
// 512B contiguous), stores 128B contiguous per lane.
__global__ __launch_bounds__(BLOCK) void hashenc_transpose(
    const float* __restrict__ ws, float* __restrict__ out, int n_points)
{
    const int n = blockIdx.x * BLOCK + (int)threadIdx.x;
    if (n >= n_points) return;

    f32x2 v[NUM_LEVELS];
#pragma unroll
    for (int l = 0; l < NUM_LEVELS; ++l)
        v[l] = reinterpret_cast<const f32x2*>(ws)[(size_t)l * n_points + n];

    f32x4* o = reinterpret_cast<f32x4*>(out + (size_t)n * (NUM_LEVELS * 2));
#pragma unroll
    for (int i = 0; i < 8; ++i) {
        f32x4 t;
        t.x = v[2*i].x;   t.y = v[2*i].y;
        t.z = v[2*i+1].x; t.w = v[2*i+1].y;
        __builtin_nontemporal_store(t, o + i);
    }
}

// Fallback (ws too small): direct strided store.
__global__ __launch_bounds__(BLOCK) void hashenc_direct(
    const float* __restrict__ x,
    const float* __restrict__ table,
    const float* __restrict__ scalings,
    const int* __restrict__ hash_offset,
    const int* __restrict__ tsp,
    float* __restrict__ out,
    int n_points)
{
    const int tid = blockIdx.x * BLOCK + (int)threadIdx.x;
    if (tid >= n_points * NUM_LEVELS) return;
    const int n = tid >> 4, l = tid & 15;

    const float s = scalings[l];
    const int off = hash_offset[l];
    const uint32_t ts = (uint32_t)tsp[0];
    const bool pow2 = (ts & (ts - 1u)) == 0u;
    const uint32_t mask = ts - 1u;

    const float sx = x[n*3]*s, sy = x[n*3+1]*s, sz = x[n*3+2]*s;
    const float fxf = floorf(sx), fyf = floorf(sy), fzf = floorf(sz);
    const float tx = sx - fxf, ty = sy - fyf, tz = sz - fzf;
    const uint32_t fxi = (uint32_t)(int)fxf, fyi = (uint32_t)(int)fyf, fzi = (uint32_t)(int)fzf;
    const uint32_t cxi = (uint32_t)(int)ceilf(sx), cyi = (uint32_t)(int)ceilf(sy), czi = (uint32_t)(int)ceilf(sz);
    const uint32_t P1 = 2654435761u, P2 = 805459861u;
    const uint32_t hyf = fyi*P1, hyc = cyi*P1, hzf = fzi*P2, hzc = czi*P2;
    uint32_t h[8] = {cxi^hyc^hzc, cxi^hyc^hzf, cxi^hyf^hzc, fxi^hyc^hzc,
                     cxi^hyf^hzf, fxi^hyc^hzf, fxi^hyf^hzc, fxi^hyf^hzf};
    const f32x2* tb = reinterpret_cast<const f32x2*>(table) + off;
    f32x2 f[8];
#pragma unroll
    for (int c = 0; c < 8; ++c) f[c] = tb[pow2 ? (h[c] & mask) : (h[c] % ts)];
    const float ux = 1.f-tx, uy = 1.f-ty, uz = 1.f-tz;
    float w[8] = {tx*ty*tz, tx*uy*tz, ux*uy*tz, ux*ty*tz,
                  tx*ty*uz, tx*uy*uz, ux*uy*uz, ux*ty*uz};
    f32x2 acc = {0.f, 0.f};
#pragma unroll
    for (int c = 0; c < 8; ++c) {
        acc.x = fmaf(w[c], f[c].x, acc.x);
        acc.y = fmaf(w[c], f[c].y, acc.y);
    }
    __builtin_nontemporal_store(acc, reinterpret_cast<f32x2*>(out) + tid);
}

extern "C" void kernel_launch(void* const* d_in, const int* in_sizes, int n_in,
                              void* d_out, int out_size, void* d_ws, size_t ws_size,
                              hipStream_t stream) {
    const float* x           = (const float*)d_in[0];
    const float* hash_table  = (const float*)d_in[1];
    const float* scalings    = (const float*)d_in[2];
    const int*   hash_offset = (const int*)d_in[3];
    const int*   table_size  = (const int*)d_in[4];
    float*       out         = (float*)d_out;

    const int n_points = in_sizes[0] / 3;
    const int bpl      = (n_points + BLOCK - 1) / BLOCK;   // blocks per level
    const size_t ws_needed = (size_t)n_points * NUM_LEVELS * 2 * sizeof(float);

    if (ws_size >= ws_needed) {
        hashenc_gather<<<NUM_LEVELS * bpl, BLOCK, 0, stream>>>(
            x, hash_table, scalings, hash_offset, table_size,
            (float*)d_ws, n_points, bpl);
        hashenc_transpose<<<bpl, BLOCK, 0, stream>>>(
            (const float*)d_ws, out, n_points);
    } else {
        const int total = n_points * NUM_LEVELS;
        hashenc_direct<<<(total + BLOCK - 1) / BLOCK, BLOCK, 0, stream>>>(
            x, hash_table, scalings, hash_offset, table_size, out, n_points);
    }
}

// Round 4
// 401.852 us; speedup vs baseline: 1.5235x; 1.3536x over previous
//
#include <hip/hip_runtime.h>
#include <cstdint>
#include <cstddef>

// Instant-NGP multires hash encoding, MI355X.
//
// Round-4: round-3's time-phased gather (unchanged, 290us, L2-resident slabs)
// + LDS-staged transpose. Round-3's transpose cost ~150us because its stores
// were 16B at 128B lane stride (quarter-line scatter). Now: block loads 256
// points x 16 levels coalesced into a padded LDS tile, then stores the 32KB
// output chunk as fully-contiguous 1KB-per-wave nt stores.

typedef float f32x2 __attribute__((ext_vector_type(2)));
typedef float f32x4 __attribute__((ext_vector_type(4)));

#define NUM_LEVELS 16
#define BLOCK 256

__global__ __launch_bounds__(BLOCK) void hashenc_gather(
    const float* __restrict__ x,
    const float* __restrict__ table,
    const float* __restrict__ scalings,
    const int* __restrict__ hash_offset,
    const int* __restrict__ tsp,
    float* __restrict__ ws,           // [L][N] f32x2, level-major
    int n_points, int bpl)            // bpl = blocks per level
{
    // Big/small alternation so slot-boundary straddles co-residence a 4MB
    // slab with a small one.
    static const int perm_arr[NUM_LEVELS] =
        {15, 0, 14, 1, 13, 2, 12, 3, 11, 4, 10, 9, 8, 7, 6, 5};

    const int bid   = (int)blockIdx.x;
    const int slot  = bid / bpl;                    // wave-uniform
    const int level = perm_arr[slot];
    const int n     = (bid - slot * bpl) * BLOCK + (int)threadIdx.x;
    if (n >= n_points) return;

    const float    s    = scalings[level];
    const int      off  = hash_offset[level];
    const uint32_t ts   = (uint32_t)tsp[0];
    const bool     pow2 = (ts & (ts - 1u)) == 0u;   // uniform branch
    const uint32_t mask = ts - 1u;

    const float px = x[n * 3 + 0];
    const float py = x[n * 3 + 1];
    const float pz = x[n * 3 + 2];

    const float sx = px * s, sy = py * s, sz = pz * s;
    const float fxf = floorf(sx), fyf = floorf(sy), fzf = floorf(sz);
    const float cxf = ceilf(sx),  cyf = ceilf(sy),  czf = ceilf(sz);
    const float tx = sx - fxf, ty = sy - fyf, tz = sz - fzf;

    const uint32_t fxi = (uint32_t)(int)fxf, fyi = (uint32_t)(int)fyf, fzi = (uint32_t)(int)fzf;
    const uint32_t cxi = (uint32_t)(int)cxf, cyi = (uint32_t)(int)cyf, czi = (uint32_t)(int)czf;

    const uint32_t P1 = 2654435761u, P2 = 805459861u;
    const uint32_t hyf = fyi * P1, hyc = cyi * P1;
    const uint32_t hzf = fzi * P2, hzc = czi * P2;

    uint32_t h[8];
    h[0] = cxi ^ hyc ^ hzc;   // v0 (c,c,c)
    h[1] = cxi ^ hyc ^ hzf;   // v1 (c,c,f)
    h[2] = cxi ^ hyf ^ hzc;   // v2 (c,f,c)
    h[3] = fxi ^ hyc ^ hzc;   // v3 (f,c,c)
    h[4] = cxi ^ hyf ^ hzf;   // v4 (c,f,f)
    h[5] = fxi ^ hyc ^ hzf;   // v5 (f,c,f)
    h[6] = fxi ^ hyf ^ hzc;   // v6 (f,f,c)
    h[7] = fxi ^ hyf ^ hzf;   // v7 (f,f,f)

    const f32x2* tb = reinterpret_cast<const f32x2*>(table) + off;

    f32x2 f[8];
#pragma unroll
    for (int c = 0; c < 8; ++c) {
        const uint32_t hm = pow2 ? (h[c] & mask) : (h[c] % ts);
        f[c] = tb[hm];
    }

    const float ux = 1.f - tx, uy = 1.f - ty, uz = 1.f - tz;
    float w[8];
    w[0] = tx * ty * tz;
    w[1] = tx * uy * tz;
    w[2] = ux * uy * tz;
    w[3] = ux * ty * tz;
    w[4] = tx * ty * uz;
    w[5] = tx * uy * uz;
    w[6] = ux * uy * uz;
    w[7] = ux * ty * uz;

    f32x2 acc = {0.f, 0.f};
#pragma unroll
    for (int c = 0; c < 8; ++c) {
        acc.x = fmaf(w[c], f[c].x, acc.x);
        acc.y = fmaf(w[c], f[c].y, acc.y);
    }

    // nt store: don't let the 67MB ws stream evict the L2-resident slab.
    f32x2* wsl = reinterpret_cast<f32x2*>(ws) + (size_t)level * n_points;
    __builtin_nontemporal_store(acc, wsl + n);
}

// ws [L][N] f32x2 -> out [N][L] f32x2 via LDS tile.
// Load: 16 coalesced 512B-per-wave level rows. Store: 8 iterations of fully
// contiguous 4KB (1KB per wave instruction) nt stores.
__global__ __launch_bounds__(BLOCK) void hashenc_transpose(
    const float* __restrict__ ws, float* __restrict__ out, int n_points)
{
    __shared__ f32x2 tile[NUM_LEVELS][BLOCK + 2];   // pad 2: phase-2 2-way banks

    const int base = (int)blockIdx.x * BLOCK;
    const int t    = (int)threadIdx.x;
    const int n    = base + t;
    const bool full = (base + BLOCK) <= n_points;

    if (full) {
#pragma unroll
        for (int l = 0; l < NUM_LEVELS; ++l)
            tile[l][t] = __builtin_nontemporal_load(
                reinterpret_cast<const f32x2*>(ws) + (size_t)l * n_points + n);
        __syncthreads();

        // Output chunk for these 256 points: 32KB contiguous.
        // f32x4 element e = i*256+t  ->  point p=e/8, level-pair j=e%8.
        const int p0 = t >> 3;
        const int j  = t & 7;
        f32x4* o = reinterpret_cast<f32x4*>(out + (size_t)base * (NUM_LEVELS * 2));
#pragma unroll
        for (int i = 0; i < 8; ++i) {
            const int p = i * 32 + p0;
            const f32x2 a = tile[2 * j][p];
            const f32x2 b = tile[2 * j + 1][p];
            f32x4 v;
            v.x = a.x; v.y = a.y; v.z = b.x; v.w = b.y;
            __builtin_nontemporal_store(v, o + i * BLOCK + t);
        }
    } else if (n < n_points) {
        // Tail block: per-thread strided path.
        f32x2 v[NUM_LEVELS];
#pragma unroll
        for (int l = 0; l < NUM_LEVELS; ++l)
            v[l] = reinterpret_cast<const f32x2*>(ws)[(size_t)l * n_points + n];
        f32x4* o = reinterpret_cast<f32x4*>(out + (size_t)n * (NUM_LEVELS * 2));
#pragma unroll
        for (int i = 0; i < 8; ++i) {
            f32x4 w;
            w.x = v[2*i].x;   w.y = v[2*i].y;
            w.z = v[2*i+1].x; w.w = v[2*i+1].y;
            __builtin_nontemporal_store(w, o + i);
        }
    }
}

// Fallback (ws too small): direct strided store.
__global__ __launch_bounds__(BLOCK) void hashenc_direct(
    const float* __restrict__ x,
    const float* __restrict__ table,
    const float* __restrict__ scalings,
    const int* __restrict__ hash_offset,
    const int* __restrict__ tsp,
    float* __restrict__ out,
    int n_points)
{
    const int tid = blockIdx.x * BLOCK + (int)threadIdx.x;
    if (tid >= n_points * NUM_LEVELS) return;
    const int n = tid >> 4, l = tid & 15;

    const float s = scalings[l];
    const int off = hash_offset[l];
    const uint32_t ts = (uint32_t)tsp[0];
    const bool pow2 = (ts & (ts - 1u)) == 0u;
    const uint32_t mask = ts - 1u;

    const float sx = x[n*3]*s, sy = x[n*3+1]*s, sz = x[n*3+2]*s;
    const float fxf = floorf(sx), fyf = floorf(sy), fzf = floorf(sz);
    const float tx = sx - fxf, ty = sy - fyf, tz = sz - fzf;
    const uint32_t fxi = (uint32_t)(int)fxf, fyi = (uint32_t)(int)fyf, fzi = (uint32_t)(int)fzf;
    const uint32_t cxi = (uint32_t)(int)ceilf(sx), cyi = (uint32_t)(int)ceilf(sy), czi = (uint32_t)(int)ceilf(sz);
    const uint32_t P1 = 2654435761u, P2 = 805459861u;
    const uint32_t hyf = fyi*P1, hyc = cyi*P1, hzf = fzi*P2, hzc = czi*P2;
    uint32_t h[8] = {cxi^hyc^hzc, cxi^hyc^hzf, cxi^hyf^hzc, fxi^hyc^hzc,
                     cxi^hyf^hzf, fxi^hyc^hzf, fxi^hyf^hzc, fxi^hyf^hzf};
    const f32x2* tb = reinterpret_cast<const f32x2*>(table) + off;
    f32x2 f[8];
#pragma unroll
    for (int c = 0; c < 8; ++c) f[c] = tb[pow2 ? (h[c] & mask) : (h[c] % ts)];
    const float ux = 1.f-tx, uy = 1.f-ty, uz = 1.f-tz;
    float w[8] = {tx*ty*tz, tx*uy*tz, ux*uy*tz, ux*ty*tz,
                  tx*ty*uz, tx*uy*uz, ux*uy*uz, ux*ty*uz};
    f32x2 acc = {0.f, 0.f};
#pragma unroll
    for (int c = 0; c < 8; ++c) {
        acc.x = fmaf(w[c], f[c].x, acc.x);
        acc.y = fmaf(w[c], f[c].y, acc.y);
    }
    __builtin_nontemporal_store(acc, reinterpret_cast<f32x2*>(out) + tid);
}

extern "C" void kernel_launch(void* const* d_in, const int* in_sizes, int n_in,
                              void* d_out, int out_size, void* d_ws, size_t ws_size,
                              hipStream_t stream) {
    const float* x           = (const float*)d_in[0];
    const float* hash_table  = (const float*)d_in[1];
    const float* scalings    = (const float*)d_in[2];
    const int*   hash_offset = (const int*)d_in[3];
    const int*   table_size  = (const int*)d_in[4];
    float*       out         = (float*)d_out;

    const int n_points = in_sizes[0] / 3;
    const int bpl      = (n_points + BLOCK - 1) / BLOCK;   // blocks per level
    const size_t ws_needed = (size_t)n_points * NUM_LEVELS * 2 * sizeof(float);

    if (ws_size >= ws_needed) {
        hashenc_gather<<<NUM_LEVELS * bpl, BLOCK, 0, stream>>>(
            x, hash_table, scalings, hash_offset, table_size,
            (float*)d_ws, n_points, bpl);
        hashenc_transpose<<<bpl, BLOCK, 0, stream>>>(
            (const float*)d_ws, out, n_points);
    } else {
        const int total = n_points * NUM_LEVELS;
        hashenc_direct<<<(total + BLOCK - 1) / BLOCK, BLOCK, 0, stream>>>(
            x, hash_table, scalings, hash_offset, table_size, out, n_points);
    }
}

// Round 5
// 351.609 us; speedup vs baseline: 1.7412x; 1.1429x over previous
//
#include <hip/hip_runtime.h>
#include <cstdint>
#include <cstddef>

// Instant-NGP multires hash encoding, MI355X.
//
// Round-5: time-phased gather (round-3) + LDS transpose (round-4) +
// X-PAIR MERGED GATHERS. The NGP hash uses multiplier 1 on the x coord:
// h = ix ^ iy*P1 ^ iz*P2. For even fx, cx=fx+1 -> h_c = h_f ^ 1, so the
// (floor-x, ceil-x) corner pair occupies one aligned 16B table block.
// Load dwordx4 covering the f-corner's block; issue the separate c-corner
// 8B load only for lanes whose c-index is in a different block (~50%).
// Wave requests per point: 512 -> ~384. The gather is MSHR/request-rate
// bound (0.375 req/cyc/CU measured), so fewer requests = proportional win.

typedef float f32x2 __attribute__((ext_vector_type(2)));
typedef float f32x4 __attribute__((ext_vector_type(4)));

#define NUM_LEVELS 16
#define BLOCK 256

__global__ __launch_bounds__(BLOCK) void hashenc_gather(
    const float* __restrict__ x,
    const float* __restrict__ table,
    const float* __restrict__ scalings,
    const int* __restrict__ hash_offset,
    const int* __restrict__ tsp,
    float* __restrict__ ws,           // [L][N] f32x2, level-major
    int n_points, int bpl)            // bpl = blocks per level
{
    // Big/small alternation so slot-boundary straddles co-residence a 4MB
    // slab with a small one.
    static const int perm_arr[NUM_LEVELS] =
        {15, 0, 14, 1, 13, 2, 12, 3, 11, 4, 10, 9, 8, 7, 6, 5};

    const int bid   = (int)blockIdx.x;
    const int slot  = bid / bpl;                    // wave-uniform
    const int level = perm_arr[slot];
    const int n     = (bid - slot * bpl) * BLOCK + (int)threadIdx.x;
    if (n >= n_points) return;

    const float    s    = scalings[level];
    const int      off  = hash_offset[level];
    const uint32_t ts   = (uint32_t)tsp[0];
    const bool     pow2 = (ts & (ts - 1u)) == 0u;   // uniform branch
    const uint32_t mask = ts - 1u;

    const float px = x[n * 3 + 0];
    const float py = x[n * 3 + 1];
    const float pz = x[n * 3 + 2];

    const float sx = px * s, sy = py * s, sz = pz * s;
    const float fxf = floorf(sx), fyf = floorf(sy), fzf = floorf(sz);
    const float cxf = ceilf(sx),  cyf = ceilf(sy),  czf = ceilf(sz);
    const float tx = sx - fxf, ty = sy - fyf, tz = sz - fzf;

    const uint32_t fxi = (uint32_t)(int)fxf, fyi = (uint32_t)(int)fyf, fzi = (uint32_t)(int)fzf;
    const uint32_t cxi = (uint32_t)(int)cxf, cyi = (uint32_t)(int)cyf, czi = (uint32_t)(int)czf;

    const uint32_t P1 = 2654435761u, P2 = 805459861u;
    const uint32_t hyf = fyi * P1, hyc = cyi * P1;
    const uint32_t hzf = fzi * P2, hzc = czi * P2;

    // y/z hash parts; per part, the two x-corners: c uses cxi, f uses fxi.
    const uint32_t A0 = hyc ^ hzc;   // c -> v0 (w0), f -> v3 (w3)
    const uint32_t A1 = hyc ^ hzf;   // c -> v1 (w1), f -> v5 (w5)
    const uint32_t A2 = hyf ^ hzc;   // c -> v2 (w2), f -> v6 (w6)
    const uint32_t A3 = hyf ^ hzf;   // c -> v4 (w4), f -> v7 (w7)

    const float ux = 1.f - tx, uy = 1.f - ty, uz = 1.f - tz;
    // Weight pairs (wc = ceil-x corner, wf = floor-x corner), per reference
    // ordering (weights inherit the original's scrambled tree; verified r1-4).
    float wc[4], wf[4];
    wc[0] = tx * ty * tz;  wf[0] = ux * ty * tz;   // v0 / v3
    wc[1] = tx * uy * tz;  wf[1] = tx * uy * uz;   // v1 / v5
    wc[2] = ux * uy * tz;  wf[2] = ux * uy * uz;   // v2 / v6
    wc[3] = tx * ty * uz;  wf[3] = ux * ty * uz;   // v4 / v7

    const f32x2* tb2 = reinterpret_cast<const f32x2*>(table) + off;
    const f32x4* tb4 = reinterpret_cast<const f32x4*>(table + (size_t)off * 2);

    f32x2 acc = {0.f, 0.f};

    if (pow2) {
        const uint32_t Aarr[4] = {A0, A1, A2, A3};
        uint32_t hf[4], hc[4], bf[4];
        bool mg[4];
#pragma unroll
        for (int j = 0; j < 4; ++j) {
            hf[j] = (fxi ^ Aarr[j]) & mask;
            hc[j] = (cxi ^ Aarr[j]) & mask;
            bf[j] = hf[j] >> 1;
            mg[j] = (hc[j] >> 1) == bf[j];
        }
        // Issue the 4 block loads first (each covers hf and hf^1).
        f32x4 q[4];
#pragma unroll
        for (int j = 0; j < 4; ++j) q[j] = tb4[bf[j]];
        // Separate c-corner loads only for unmerged lanes (exec-masked:
        // requests only from active lanes).
        f32x2 el[4];
#pragma unroll
        for (int j = 0; j < 4; ++j) {
            el[j].x = 0.f; el[j].y = 0.f;
            if (!mg[j]) el[j] = tb2[hc[j]];
        }
#pragma unroll
        for (int j = 0; j < 4; ++j) {
            const f32x2 qlo = {q[j].x, q[j].y};
            const f32x2 qhi = {q[j].z, q[j].w};
            const f32x2 ef = (hf[j] & 1u) ? qhi : qlo;
            const f32x2 eh = (hc[j] & 1u) ? qhi : qlo;
            const f32x2 ec = mg[j] ? eh : el[j];
            acc.x = fmaf(wf[j], ef.x, acc.x);
            acc.y = fmaf(wf[j], ef.y, acc.y);
            acc.x = fmaf(wc[j], ec.x, acc.x);
            acc.y = fmaf(wc[j], ec.y, acc.y);
        }
    } else {
        // Generic path (non-pow2 table): plain 8 gathers.
        uint32_t h[8];
        h[0] = (cxi ^ A0) % ts; h[3] = (fxi ^ A0) % ts;
        h[1] = (cxi ^ A1) % ts; h[5] = (fxi ^ A1) % ts;
        h[2] = (cxi ^ A2) % ts; h[6] = (fxi ^ A2) % ts;
        h[4] = (cxi ^ A3) % ts; h[7] = (fxi ^ A3) % ts;
        f32x2 f[8];
#pragma unroll
        for (int c = 0; c < 8; ++c) f[c] = tb2[h[c]];
        const float w[8] = {wc[0], wc[1], wc[2], wf[0], wc[3], wf[1], wf[2], wf[3]};
#pragma unroll
        for (int c = 0; c < 8; ++c) {
            acc.x = fmaf(w[c], f[c].x, acc.x);
            acc.y = fmaf(w[c], f[c].y, acc.y);
        }
    }

    // nt store: don't let the 67MB ws stream evict the L2-resident slab.
    f32x2* wsl = reinterpret_cast<f32x2*>(ws) + (size_t)level * n_points;
    __builtin_nontemporal_store(acc, wsl + n);
}

// ws [L][N] f32x2 -> out [N][L] f32x2 via LDS tile.
__global__ __launch_bounds__(BLOCK) void hashenc_transpose(
    const float* __restrict__ ws, float* __restrict__ out, int n_points)
{
    __shared__ f32x2 tile[NUM_LEVELS][BLOCK + 2];

    const int base = (int)blockIdx.x * BLOCK;
    const int t    = (int)threadIdx.x;
    const int n    = base + t;
    const bool full = (base + BLOCK) <= n_points;

    if (full) {
#pragma unroll
        for (int l = 0; l < NUM_LEVELS; ++l)
            tile[l][t] = __builtin_nontemporal_load(
                reinterpret_cast<const f32x2*>(ws) + (size_t)l * n_points + n);
        __syncthreads();

        const int p0 = t >> 3;
        const int j  = t & 7;
        f32x4* o = reinterpret_cast<f32x4*>(out + (size_t)base * (NUM_LEVELS * 2));
#pragma unroll
        for (int i = 0; i < 8; ++i) {
            const int p = i * 32 + p0;
            const f32x2 a = tile[2 * j][p];
            const f32x2 b = tile[2 * j + 1][p];
            f32x4 v;
            v.x = a.x; v.y = a.y; v.z = b.x; v.w = b.y;
            __builtin_nontemporal_store(v, o + i * BLOCK + t);
        }
    } else if (n < n_points) {
        f32x2 v[NUM_LEVELS];
#pragma unroll
        for (int l = 0; l < NUM_LEVELS; ++l)
            v[l] = reinterpret_cast<const f32x2*>(ws)[(size_t)l * n_points + n];
        f32x4* o = reinterpret_cast<f32x4*>(out + (size_t)n * (NUM_LEVELS * 2));
#pragma unroll
        for (int i = 0; i < 8; ++i) {
            f32x4 w;
            w.x = v[2*i].x;   w.y = v[2*i].y;
            w.z = v[2*i+1].x; w.w = v[2*i+1].y;
            __builtin_nontemporal_store(w, o + i);
        }
    }
}

// Fallback (ws too small): direct strided store.
__global__ __launch_bounds__(BLOCK) void hashenc_direct(
    const float* __restrict__ x,
    const float* __restrict__ table,
    const float* __restrict__ scalings,
    const int* __restrict__ hash_offset,
    const int* __restrict__ tsp,
    float* __restrict__ out,
    int n_points)
{
    const int tid = blockIdx.x * BLOCK + (int)threadIdx.x;
    if (tid >= n_points * NUM_LEVELS) return;
    const int n = tid >> 4, l = tid & 15;

    const float s = scalings[l];
    const int off = hash_offset[l];
    const uint32_t ts = (uint32_t)tsp[0];
    const bool pow2 = (ts & (ts - 1u)) == 0u;
    const uint32_t mask = ts - 1u;

    const float sx = x[n*3]*s, sy = x[n*3+1]*s, sz = x[n*3+2]*s;
    const float fxf = floorf(sx), fyf = floorf(sy), fzf = floorf(sz);
    const float tx = sx - fxf, ty = sy - fyf, tz = sz - fzf;
    const uint32_t fxi = (uint32_t)(int)fxf, fyi = (uint32_t)(int)fyf, fzi = (uint32_t)(int)fzf;
    const uint32_t cxi = (uint32_t)(int)ceilf(sx), cyi = (uint32_t)(int)ceilf(sy), czi = (uint32_t)(int)ceilf(sz);
    const uint32_t P1 = 2654435761u, P2 = 805459861u;
    const uint32_t hyf = fyi*P1, hyc = cyi*P1, hzf = fzi*P2, hzc = czi*P2;
    uint32_t h[8] = {cxi^hyc^hzc, cxi^hyc^hzf, cxi^hyf^hzc, fxi^hyc^hzc,
                     cxi^hyf^hzf, fxi^hyc^hzf, fxi^hyf^hzc, fxi^hyf^hzf};
    const f32x2* tb = reinterpret_cast<const f32x2*>(table) + off;
    f32x2 f[8];
#pragma unroll
    for (int c = 0; c < 8; ++c) f[c] = tb[pow2 ? (h[c] & mask) : (h[c] % ts)];
    const float ux = 1.f-tx, uy = 1.f-ty, uz = 1.f-tz;
    float w[8] = {tx*ty*tz, tx*uy*tz, ux*uy*tz, ux*ty*tz,
                  tx*ty*uz, tx*uy*uz, ux*uy*uz, ux*ty*uz};
    f32x2 acc = {0.f, 0.f};
#pragma unroll
    for (int c = 0; c < 8; ++c) {
        acc.x = fmaf(w[c], f[c].x, acc.x);
        acc.y = fmaf(w[c], f[c].y, acc.y);
    }
    __builtin_nontemporal_store(acc, reinterpret_cast<f32x2*>(out) + tid);
}

extern "C" void kernel_launch(void* const* d_in, const int* in_sizes, int n_in,
                              void* d_out, int out_size, void* d_ws, size_t ws_size,
                              hipStream_t stream) {
    const float* x           = (const float*)d_in[0];
    const float* hash_table  = (const float*)d_in[1];
    const float* scalings    = (const float*)d_in[2];
    const int*   hash_offset = (const int*)d_in[3];
    const int*   table_size  = (const int*)d_in[4];
    float*       out         = (float*)d_out;

    const int n_points = in_sizes[0] / 3;
    const int bpl      = (n_points + BLOCK - 1) / BLOCK;   // blocks per level
    const size_t ws_needed = (size_t)n_points * NUM_LEVELS * 2 * sizeof(float);

    if (ws_size >= ws_needed) {
        hashenc_gather<<<NUM_LEVELS * bpl, BLOCK, 0, stream>>>(
            x, hash_table, scalings, hash_offset, table_size,
            (float*)d_ws, n_points, bpl);
        hashenc_transpose<<<bpl, BLOCK, 0, stream>>>(
            (const float*)d_ws, out, n_points);
    } else {
        const int total = n_points * NUM_LEVELS;
        hashenc_direct<<<(total + BLOCK - 1) / BLOCK, BLOCK, 0, stream>>>(
            x, hash_table, scalings, hash_offset, table_size, out, n_points);
    }
}